// Round 5
// baseline (257.648 us; speedup 1.0000x reference)
//
#include <hip/hip_runtime.h>

// Fused KernelWarehouse dynamic conv, round 3 (resubmit — container died):
//   logits = 1x1 conv (attn_w) -> softmax over K=4 -> 3x3 convs -> mixture.
// R3 change: 16x32 tiles -> 2048 blocks = 8 blocks/CU (was 4, grid-limited,
// Occupancy 44.7%). 8 independent barrier domains per CU interleave the
// vmcnt-drain/barrier stalls that capped R2 at ~131us. Per-thread strip is
// now 1x2 (16 rows x 16 colgroups), NS=3 staging regs, fits 64 VGPR for
// __launch_bounds__(256,8). LDS 11.8KB/block x 8 = 94KB/CU. Read-bank
// pattern (9r+2cg)%32 = exact 2-way = free (m136).

#define HH 256
#define WW 256
#define CH 64
#define TROWS 16                 // tile rows
#define TCOLS 32                 // tile cols
#define CPB 4                    // channels staged per barrier pair
#define NG (CH / CPB)            // 16 groups
#define ROWS 18                  // tile rows incl. halo
#define NC4 10                   // float4 per staged row ([w0-4, w0+36))
#define LDSS 41                  // LDS row stride in floats (odd -> 2-way banks max)
#define CH_STRIDE (ROWS * LDSS)  // 738 floats per channel
#define TV (CPB * ROWS * NC4)    // 720 float4 per group
#define NS 3                     // ceil(TV/256) staging regs per thread

__global__ __launch_bounds__(256, 8) void kwdc_fused(
    const float* __restrict__ x,       // [B,C,H,W]
    const float* __restrict__ weight,  // [K,C,3,3]
    const float* __restrict__ attn_w,  // [K,C]
    const float* __restrict__ attn_b,  // [K]
    float* __restrict__ out)           // [B,1,H,W]
{
    __shared__ float lds[CPB * CH_STRIDE];   // 11.8 KB

    const int tid = threadIdx.x;
    const int tw = blockIdx.x;   // 0..7
    const int th = blockIdx.y;   // 0..15
    const int b  = blockIdx.z;   // 0..15

    const int r  = tid >> 4;     // 0..15 row in tile
    const int cg = tid & 15;     // col group
    const int wb = cg * 2;       // col base (2-wide strip)

    const int h0 = th * TROWS;
    const int w0 = tw * TCOLS;

    const float* xb = x + (size_t)b * CH * HH * WW;

    // ---- per-s staging metadata (tid-dependent only) ----
    int  s_ch[NS];      // channel within group
    int  s_gofs[NS];    // offset within a channel plane
    int  s_lofs[NS];    // LDS float offset
    bool s_val[NS];     // in-bounds global load
    bool s_act[NS];     // participates
#pragma unroll
    for (int s = 0; s < NS; ++s) {
        int i = tid + s * 256;
        bool act = i < TV;
        int col4  = i % NC4;
        int rowch = i / NC4;
        int row   = rowch % ROWS;
        int ch    = rowch / ROWS;
        int gh  = h0 + row - 1;
        int gw0 = w0 - 4 + col4 * 4;      // 16B-aligned; fully in or fully out
        s_act[s]  = act;
        s_val[s]  = act && ((unsigned)gh < HH) && ((unsigned)gw0 < WW);
        s_gofs[s] = gh * WW + gw0;
        s_lofs[s] = ch * CH_STRIDE + row * LDSS + col4 * 4;
        s_ch[s]   = ch;
    }

    float4 stg[NS];

    auto load_group = [&](int g) {
#pragma unroll
        for (int s = 0; s < NS; ++s) {
            float4 v = {0.f, 0.f, 0.f, 0.f};
            if (s_val[s]) {
                const float* p = xb + (size_t)(g * CPB + s_ch[s]) * (HH * WW) + s_gofs[s];
                v = *reinterpret_cast<const float4*>(p);
            }
            stg[s] = v;
        }
    };

    float conv[4][2];
    float logit[4][2];
#pragma unroll
    for (int k = 0; k < 4; ++k)
#pragma unroll
        for (int p = 0; p < 2; ++p) { conv[k][p] = 0.f; logit[k][p] = 0.f; }

    load_group(0);

    for (int g = 0; g < NG; ++g) {
        // ---- staged regs -> LDS (dep on loads waits vmcnt naturally) ----
#pragma unroll
        for (int s = 0; s < NS; ++s) {
            if (s_act[s]) {
                float* q = &lds[s_lofs[s]];
                q[0] = stg[s].x; q[1] = stg[s].y; q[2] = stg[s].z; q[3] = stg[s].w;
            }
        }
        __syncthreads();

        // ---- prefetch next group; latency hides under compute ----
        if (g + 1 < NG) load_group(g + 1);

        // ---- compute 4 channels from LDS ----
#pragma unroll
        for (int c = 0; c < CPB; ++c) {
            const int gc = g * CPB + c;
            const float* tp = &lds[c * CH_STRIDE + r * LDSS + wb + 3];
            float rv[3][4];
#pragma unroll
            for (int i = 0; i < 3; ++i)
#pragma unroll
                for (int j = 0; j < 4; ++j)
                    rv[i][j] = tp[i * LDSS + j];

#pragma unroll
            for (int k = 0; k < 4; ++k) {
                const float* wp = weight + (k * CH + gc) * 9;   // wave-uniform
                const float w00 = wp[0], w01 = wp[1], w02 = wp[2];
                const float w10 = wp[3], w11 = wp[4], w12 = wp[5];
                const float w20 = wp[6], w21 = wp[7], w22 = wp[8];
                const float aw  = attn_w[k * CH + gc];
#pragma unroll
                for (int p = 0; p < 2; ++p) {
                    float acc = conv[k][p];
                    acc = fmaf(rv[0][p],     w00, acc);
                    acc = fmaf(rv[0][p + 1], w01, acc);
                    acc = fmaf(rv[0][p + 2], w02, acc);
                    acc = fmaf(rv[1][p],     w10, acc);
                    acc = fmaf(rv[1][p + 1], w11, acc);
                    acc = fmaf(rv[1][p + 2], w12, acc);
                    acc = fmaf(rv[2][p],     w20, acc);
                    acc = fmaf(rv[2][p + 1], w21, acc);
                    acc = fmaf(rv[2][p + 2], w22, acc);
                    conv[k][p] = acc;
                    logit[k][p] = fmaf(rv[1][p + 1], aw, logit[k][p]);
                }
            }
        }
        __syncthreads();   // LDS reads done before next group's writes
    }

    // ---- epilogue: softmax over K=4 + mixture ----
    const float b0 = attn_b[0], b1 = attn_b[1], b2 = attn_b[2], b3 = attn_b[3];
    float2 o;
    float* op = &o.x;
#pragma unroll
    for (int p = 0; p < 2; ++p) {
        float l0 = logit[0][p] + b0;
        float l1 = logit[1][p] + b1;
        float l2 = logit[2][p] + b2;
        float l3 = logit[3][p] + b3;
        float m = fmaxf(fmaxf(l0, l1), fmaxf(l2, l3));
        float e0 = __expf(l0 - m), e1 = __expf(l1 - m);
        float e2 = __expf(l2 - m), e3 = __expf(l3 - m);
        float s = e0 + e1 + e2 + e3;
        float num = conv[0][p] * e0 + conv[1][p] * e1
                  + conv[2][p] * e2 + conv[3][p] * e3;
        op[p] = num / s;
    }
    size_t oidx = (size_t)b * HH * WW + (size_t)(h0 + r) * WW + (w0 + wb);
    *reinterpret_cast<float2*>(out + oidx) = o;
}

extern "C" void kernel_launch(void* const* d_in, const int* in_sizes, int n_in,
                              void* d_out, int out_size, void* d_ws, size_t ws_size,
                              hipStream_t stream) {
    const float* x      = (const float*)d_in[0];
    const float* weight = (const float*)d_in[1];
    const float* attn_w = (const float*)d_in[2];
    const float* attn_b = (const float*)d_in[3];
    float* out = (float*)d_out;

    dim3 grid(8, 16, 16);   // (W/32, H/16, B)
    kwdc_fused<<<grid, 256, 0, stream>>>(x, weight, attn_w, attn_b, out);
}

// Round 6
// 115.941 us; speedup vs baseline: 2.2222x; 2.2222x over previous
//
#include <hip/hip_runtime.h>

// Fused KernelWarehouse dynamic conv, round 4:
//   logits = 1x1 conv (attn_w) -> softmax over K=4 -> 3x3 convs -> mixture.
// R5 post-mortem: 16x32 tiles raised occupancy (80%) but VALUBusy FELL and
// FETCH rose 60% (halo line-split no longer L2-absorbed) -> revert to 32x32.
// R6 change vs R2: double-buffered LDS (CPB=2, NG=32), ONE barrier per group:
//   { write g+1 -> buf[(g+1)&1]; issue loads g+2; compute g from buf[g&1]; bar }
// Compute starts right after each barrier (data landed an iteration earlier);
// prefetch is 2 groups (~2500 cyc) deep >> 900-cyc HBM latency. Same 22.3 KB
// LDS, same 361 MB fetch geometry, odd-41 stride (<=2-way banks = free).

#define HH 256
#define WW 256
#define CH 64
#define TILE 32
#define CPB 2                    // channels per LDS buffer
#define NG (CH / CPB)            // 32 groups
#define ROWS 34                  // tile rows incl. halo
#define NC4 10                   // float4 per staged row ([w0-4, w0+36))
#define LDSS 41                  // LDS row stride in floats (odd -> <=2-way banks)
#define CH_STRIDE (ROWS * LDSS)  // 1394 floats per channel
#define TV (CPB * ROWS * NC4)    // 680 float4 per group
#define NS 3                     // ceil(TV/256) staging regs per thread

__global__ __launch_bounds__(256, 4) void kwdc_fused(
    const float* __restrict__ x,       // [B,C,H,W]
    const float* __restrict__ weight,  // [K,C,3,3]
    const float* __restrict__ attn_w,  // [K,C]
    const float* __restrict__ attn_b,  // [K]
    float* __restrict__ out)           // [B,1,H,W]
{
    __shared__ float lds[2][CPB * CH_STRIDE];   // 2 x 11.15 KB = 22.3 KB

    const int tid = threadIdx.x;
    const int tw = blockIdx.x;   // 0..7
    const int th = blockIdx.y;   // 0..7
    const int b  = blockIdx.z;   // 0..15

    const int r  = tid >> 3;     // 0..31 row in tile
    const int cg = tid & 7;      // col group
    const int wb = cg * 4;       // col base (4-wide strip)

    const int h0 = th * TILE;
    const int w0 = tw * TILE;

    const float* xb = x + (size_t)b * CH * HH * WW;

    // ---- per-s staging metadata (tid-dependent only) ----
    int  s_ch[NS];      // channel within group (0..CPB-1)
    int  s_gofs[NS];    // offset within a channel plane
    int  s_lofs[NS];    // LDS float offset within a buffer
    bool s_val[NS];     // in-bounds global load
    bool s_act[NS];     // participates
#pragma unroll
    for (int s = 0; s < NS; ++s) {
        int i = tid + s * 256;
        bool act = i < TV;
        int col4  = i % NC4;
        int rowch = i / NC4;
        int row   = rowch % ROWS;
        int ch    = rowch / ROWS;
        int gh  = h0 + row - 1;
        int gw0 = w0 - 4 + col4 * 4;      // 16B-aligned; fully in or fully out
        s_act[s]  = act;
        s_val[s]  = act && ((unsigned)gh < HH) && ((unsigned)gw0 < WW);
        s_gofs[s] = gh * WW + gw0;
        s_lofs[s] = ch * CH_STRIDE + row * LDSS + col4 * 4;
        s_ch[s]   = ch;
    }

    float4 stg[NS];

    auto load_group = [&](int g) {
#pragma unroll
        for (int s = 0; s < NS; ++s) {
            float4 v = {0.f, 0.f, 0.f, 0.f};
            if (s_val[s]) {
                const float* p = xb + (size_t)(g * CPB + s_ch[s]) * (HH * WW) + s_gofs[s];
                v = *reinterpret_cast<const float4*>(p);
            }
            stg[s] = v;
        }
    };

    auto store_group = [&](int buf) {
#pragma unroll
        for (int s = 0; s < NS; ++s) {
            if (s_act[s]) {
                float* q = &lds[buf][s_lofs[s]];
                q[0] = stg[s].x; q[1] = stg[s].y; q[2] = stg[s].z; q[3] = stg[s].w;
            }
        }
    };

    float conv[4][4];
    float logit[4][4];
#pragma unroll
    for (int k = 0; k < 4; ++k)
#pragma unroll
        for (int p = 0; p < 4; ++p) { conv[k][p] = 0.f; logit[k][p] = 0.f; }

    // ---- prologue: fill buf0, start loads for group 1 ----
    load_group(0);
    store_group(0);
    load_group(1);
    __syncthreads();    // buf0 ready for everyone

    for (int g = 0; g < NG; ++g) {
        // write next group's data into the other buffer (waits its vmcnt),
        // then immediately issue loads two groups ahead
        if (g + 1 < NG) {
            store_group((g + 1) & 1);
            if (g + 2 < NG) load_group(g + 2);
        }

        // ---- compute CPB channels from buf[g&1] (ready since last barrier) ----
#pragma unroll
        for (int c = 0; c < CPB; ++c) {
            const int gc = g * CPB + c;
            const float* tp = &lds[g & 1][c * CH_STRIDE + r * LDSS + wb + 3];
            float rv[3][6];
#pragma unroll
            for (int i = 0; i < 3; ++i)
#pragma unroll
                for (int j = 0; j < 6; ++j)
                    rv[i][j] = tp[i * LDSS + j];

#pragma unroll
            for (int k = 0; k < 4; ++k) {
                const float* wp = weight + (k * CH + gc) * 9;   // wave-uniform
                const float w00 = wp[0], w01 = wp[1], w02 = wp[2];
                const float w10 = wp[3], w11 = wp[4], w12 = wp[5];
                const float w20 = wp[6], w21 = wp[7], w22 = wp[8];
                const float aw  = attn_w[k * CH + gc];
#pragma unroll
                for (int p = 0; p < 4; ++p) {
                    float acc = conv[k][p];
                    acc = fmaf(rv[0][p],     w00, acc);
                    acc = fmaf(rv[0][p + 1], w01, acc);
                    acc = fmaf(rv[0][p + 2], w02, acc);
                    acc = fmaf(rv[1][p],     w10, acc);
                    acc = fmaf(rv[1][p + 1], w11, acc);
                    acc = fmaf(rv[1][p + 2], w12, acc);
                    acc = fmaf(rv[2][p],     w20, acc);
                    acc = fmaf(rv[2][p + 1], w21, acc);
                    acc = fmaf(rv[2][p + 2], w22, acc);
                    conv[k][p] = acc;
                    logit[k][p] = fmaf(rv[1][p + 1], aw, logit[k][p]);
                }
            }
        }
        // one barrier per group: reads of buf[g&1] done (it is rewritten at
        // iter g+1), writes of buf[(g+1)&1] visible for iter g+1's compute
        __syncthreads();
    }

    // ---- epilogue: softmax over K=4 + mixture ----
    const float b0 = attn_b[0], b1 = attn_b[1], b2 = attn_b[2], b3 = attn_b[3];
    float4 o;
    float* op = &o.x;
#pragma unroll
    for (int p = 0; p < 4; ++p) {
        float l0 = logit[0][p] + b0;
        float l1 = logit[1][p] + b1;
        float l2 = logit[2][p] + b2;
        float l3 = logit[3][p] + b3;
        float m = fmaxf(fmaxf(l0, l1), fmaxf(l2, l3));
        float e0 = __expf(l0 - m), e1 = __expf(l1 - m);
        float e2 = __expf(l2 - m), e3 = __expf(l3 - m);
        float s = e0 + e1 + e2 + e3;
        float num = conv[0][p] * e0 + conv[1][p] * e1
                  + conv[2][p] * e2 + conv[3][p] * e3;
        op[p] = num / s;
    }
    size_t oidx = (size_t)b * HH * WW + (size_t)(h0 + r) * WW + (w0 + wb);
    *reinterpret_cast<float4*>(out + oidx) = o;
}

extern "C" void kernel_launch(void* const* d_in, const int* in_sizes, int n_in,
                              void* d_out, int out_size, void* d_ws, size_t ws_size,
                              hipStream_t stream) {
    const float* x      = (const float*)d_in[0];
    const float* weight = (const float*)d_in[1];
    const float* attn_w = (const float*)d_in[2];
    const float* attn_b = (const float*)d_in[3];
    float* out = (float*)d_out;

    dim3 grid(8, 8, 16);   // (W/32, H/32, B)
    kwdc_fused<<<grid, 256, 0, stream>>>(x, weight, attn_w, attn_b, out);
}